// Round 5
// baseline (206.032 us; speedup 1.0000x reference)
//
#include <hip/hip_runtime.h>
#include <hip/hip_bf16.h>

typedef __attribute__((ext_vector_type(8))) short  bf16x8;
typedef __attribute__((ext_vector_type(4))) float  f32x4;
typedef __attribute__((ext_vector_type(4))) int    i32x4;
typedef __attribute__((address_space(3))) void       as3void;
typedef const __attribute__((address_space(1))) void as1void;

#define B_   8
#define R_   4
#define N_   2048
#define S_   6
#define DIN  32
#define DOUT 32
#define NT   32    // K-tiles of BK=64

// ---------------------------------------------------------------------------
// Pre-kernel: XW_T[b][r][e][m] = bf16( coef[r] * sum_d X[b,r,m,d] * fc_w[r,d,e] )
// ---------------------------------------------------------------------------
__global__ __launch_bounds__(256) void prep_xw(
    const float* __restrict__ theta, const float* __restrict__ tpar,
    const float* __restrict__ X,     const float* __restrict__ fcw,
    __hip_bfloat16* __restrict__ xwt)
{
    int br    = blockIdx.x >> 5;
    int mtile = blockIdx.x & 31;
    int r     = br & 3;
    int t     = threadIdx.x;
    int m     = mtile * 64 + (t & 63);
    int egrp  = t >> 6;

    float coef = 0.f;
#pragma unroll
    for (int s = 0; s < S_; ++s) coef += theta[r * S_ + s] * tpar[r * S_ + s];

    const float* xrow = X + ((size_t)br * N_ + m) * DIN;
    float xr[DIN];
#pragma unroll
    for (int i = 0; i < DIN / 4; ++i) {
        f32x4 v = *(const f32x4*)(xrow + i * 4);
        xr[i * 4 + 0] = v.x; xr[i * 4 + 1] = v.y;
        xr[i * 4 + 2] = v.z; xr[i * 4 + 3] = v.w;
    }
#pragma unroll
    for (int eb = 0; eb < 8; ++eb) {
        int e = egrp * 8 + eb;
        float acc = 0.f;
#pragma unroll
        for (int d = 0; d < DIN; ++d) acc += xr[d] * fcw[(r * DIN + d) * DOUT + e];
        xwt[((size_t)br * DOUT + e) * N_ + m] = __float2bfloat16(coef * acc);
    }
}

// ---------------------------------------------------------------------------
// Main fused kernel. 4 waves/block (wave r = relation r), 32-row n-tile
// (2 M-tiles per wave share every B fragment -> B L2-traffic halved).
// XCD-chunked swizzle: XCD x runs batch b=x only -> per-XCD xwt working set
// 512KB, L2-resident. A staged via global_load_lds DMA (BK=64, 256B/row),
// double-buffered, counted vmcnt(12), no barriers in K-loop.
// XOR swizzle ((row&7)<<4) pre-applied to DMA SOURCE (linear dest, G21).
// ---------------------------------------------------------------------------
__global__ __launch_bounds__(256) void fused_main(
    const float* __restrict__ A,   const __hip_bfloat16* __restrict__ xwt,
    const float* __restrict__ fcb, const float* __restrict__ cw,
    const float* __restrict__ cb,  const float* __restrict__ p0p,
    const float* __restrict__ p1p, float* __restrict__ out)
{
    __shared__ char smem[65536];   // [buf(2)][wave(4)][32 rows][64 k f32] = 64KB

    int bid  = blockIdx.x;                 // 512 blocks; 512%8==0 -> simple swizzle
    int swz  = (bid & 7) * 64 + (bid >> 3);
    int b    = swz >> 6;                   // one batch per XCD
    int tile = swz & 63;                   // 64 n-tiles of 32 rows
    int n0   = tile * 32;
    int t    = threadIdx.x;
    int r    = t >> 6;
    int l    = t & 63;
    int row16 = l & 15;
    int kg    = l >> 4;
    int swzr  = (row16 & 7) << 4;          // read-side XOR for rt row16 (rows 16+x share x&7)
    int ldsbase = r * 8192;

    // DMA source pointers: instr i covers rows {4i + (l>>4)} x 256B chunk,
    // 16 lanes per row, source byte (j*16)^((row&7)<<4), j = l&15.
    const char* Ab = (const char*)(A + (((size_t)(b * R_ + r)) * N_ + n0) * N_);
    const char* srcp[8];
#pragma unroll
    for (int i = 0; i < 8; ++i) {
        int row = 4 * i + (l >> 4);
        srcp[i] = Ab + (size_t)row * (N_ * 4) + (((l & 15) * 16) ^ ((row & 7) << 4));
    }

    // B pointers: e-half eh, k = kt*64 + ks*32 + kg*8  (ushort elements)
    const ushort* xw  = (const ushort*)xwt + (size_t)(b * R_ + r) * DOUT * N_;
    const ushort* bp0 = xw + (size_t)row16 * N_        + kg * 8;
    const ushort* bp1 = xw + (size_t)(16 + row16) * N_ + kg * 8;

#define STAGE_A(CUR, KT) do {                                                    \
    _Pragma("unroll")                                                            \
    for (int i_ = 0; i_ < 8; ++i_) {                                             \
        __builtin_amdgcn_global_load_lds(                                        \
            (as1void*)(srcp[i_] + (size_t)(KT) * 256),                           \
            (as3void*)&smem[(CUR) * 32768 + ldsbase + i_ * 1024], 16, 0, 0);     \
    } } while (0)

#define LOADB(P, KT) do {                                                        \
    asm volatile("global_load_dwordx4 %0, %1, off" : "=v"(P##0) : "v"(bp0 + (KT) * 64 +  0)); \
    asm volatile("global_load_dwordx4 %0, %1, off" : "=v"(P##1) : "v"(bp0 + (KT) * 64 + 32)); \
    asm volatile("global_load_dwordx4 %0, %1, off" : "=v"(P##2) : "v"(bp1 + (KT) * 64 +  0)); \
    asm volatile("global_load_dwordx4 %0, %1, off" : "=v"(P##3) : "v"(bp1 + (KT) * 64 + 32)); \
    } while (0)

    f32x4 acc00 = {0.f,0.f,0.f,0.f}, acc01 = {0.f,0.f,0.f,0.f};
    f32x4 acc10 = {0.f,0.f,0.f,0.f}, acc11 = {0.f,0.f,0.f,0.f};
    i32x4 bc0, bc1, bc2, bc3, bn0, bn1, bn2, bn3;

    STAGE_A(0, 0);
    LOADB(bc, 0);

#pragma unroll 2
    for (int kt = 0; kt < NT; ++kt) {
        int cur = kt & 1;
        __builtin_amdgcn_sched_barrier(0);
        if (kt < NT - 1) {
            STAGE_A(cur ^ 1, kt + 1);
            LOADB(bn, kt + 1);
            __builtin_amdgcn_sched_barrier(0);
            asm volatile("s_waitcnt vmcnt(12)" ::: "memory");  // cur's 12 done
        } else {
            __builtin_amdgcn_sched_barrier(0);
            asm volatile("s_waitcnt vmcnt(0)" ::: "memory");
        }
        __builtin_amdgcn_sched_barrier(0);

        {   // COMPUTE on buf[cur]: 2 k-steps x 2 row-tiles x 2 e-halves
            const char* abuf = &smem[cur * 32768 + ldsbase];
#define KSTEP(KS, BA, BB) do {                                                   \
    f32x4 lo0 = *(const f32x4*)(abuf + (row16      ) * 256 + (((KS)*128 + kg*32 +  0) ^ swzr)); \
    f32x4 hi0 = *(const f32x4*)(abuf + (row16      ) * 256 + (((KS)*128 + kg*32 + 16) ^ swzr)); \
    f32x4 lo1 = *(const f32x4*)(abuf + (row16 + 16 ) * 256 + (((KS)*128 + kg*32 +  0) ^ swzr)); \
    f32x4 hi1 = *(const f32x4*)(abuf + (row16 + 16 ) * 256 + (((KS)*128 + kg*32 + 16) ^ swzr)); \
    i32x4 av0, av1;                                                              \
    asm("v_cvt_pk_bf16_f32 %0, %1, %2" : "=v"(av0.x) : "v"(lo0.x), "v"(lo0.y));  \
    asm("v_cvt_pk_bf16_f32 %0, %1, %2" : "=v"(av0.y) : "v"(lo0.z), "v"(lo0.w));  \
    asm("v_cvt_pk_bf16_f32 %0, %1, %2" : "=v"(av0.z) : "v"(hi0.x), "v"(hi0.y));  \
    asm("v_cvt_pk_bf16_f32 %0, %1, %2" : "=v"(av0.w) : "v"(hi0.z), "v"(hi0.w));  \
    asm("v_cvt_pk_bf16_f32 %0, %1, %2" : "=v"(av1.x) : "v"(lo1.x), "v"(lo1.y));  \
    asm("v_cvt_pk_bf16_f32 %0, %1, %2" : "=v"(av1.y) : "v"(lo1.z), "v"(lo1.w));  \
    asm("v_cvt_pk_bf16_f32 %0, %1, %2" : "=v"(av1.z) : "v"(hi1.x), "v"(hi1.y));  \
    asm("v_cvt_pk_bf16_f32 %0, %1, %2" : "=v"(av1.w) : "v"(hi1.z), "v"(hi1.w));  \
    bf16x8 a0 = __builtin_bit_cast(bf16x8, av0);                                 \
    bf16x8 a1 = __builtin_bit_cast(bf16x8, av1);                                 \
    acc00 = __builtin_amdgcn_mfma_f32_16x16x32_bf16(a0, __builtin_bit_cast(bf16x8, BA), acc00, 0, 0, 0); \
    acc01 = __builtin_amdgcn_mfma_f32_16x16x32_bf16(a0, __builtin_bit_cast(bf16x8, BB), acc01, 0, 0, 0); \
    acc10 = __builtin_amdgcn_mfma_f32_16x16x32_bf16(a1, __builtin_bit_cast(bf16x8, BA), acc10, 0, 0, 0); \
    acc11 = __builtin_amdgcn_mfma_f32_16x16x32_bf16(a1, __builtin_bit_cast(bf16x8, BB), acc11, 0, 0, 0); \
    } while (0)
            KSTEP(0, bc0, bc2);
            KSTEP(1, bc1, bc3);
#undef KSTEP
        }
        bc0 = bn0; bc1 = bn1; bc2 = bn2; bc3 = bn3;
    }
#undef STAGE_A
#undef LOADB

    float p0 = p0p[0], p1 = p1p[0];

    __syncthreads();   // all waves done with A buffers before hlds overlays smem
    float (*hlds)[32][DOUT + 1] = (float (*)[32][DOUT + 1])(void*)smem;
#pragma unroll
    for (int j = 0; j < 4; ++j) {
        int rw = kg * 4 + j;
        float fb0 = fcb[r * DOUT + row16];
        float fb1 = fcb[r * DOUT + 16 + row16];
        float v00 = acc00[j] + fb0, v01 = acc01[j] + fb1;
        float v10 = acc10[j] + fb0, v11 = acc11[j] + fb1;
        hlds[r][rw][row16]           = v00 >= 0.f ? v00 : p0 * v00;
        hlds[r][rw][16 + row16]      = v01 >= 0.f ? v01 : p0 * v01;
        hlds[r][16 + rw][row16]      = v10 >= 0.f ? v10 : p0 * v10;
        hlds[r][16 + rw][16 + row16] = v11 >= 0.f ? v11 : p0 * v11;
    }
    __syncthreads();

    int q = r;
    float c0 = cw[q * R_ + 0], c1 = cw[q * R_ + 1];
    float c2 = cw[q * R_ + 2], c3 = cw[q * R_ + 3];
    float cbq = cb[q];
    int e  = l & 31;
    int half = l >> 5;
#pragma unroll
    for (int i = 0; i < 16; ++i) {
        int row = half * 16 + i;
        float mx = cbq + c0 * hlds[0][row][e] + c1 * hlds[1][row][e]
                       + c2 * hlds[2][row][e] + c3 * hlds[3][row][e];
        float lat = mx >= 0.f ? mx : p1 * mx;
        out[(((size_t)b * R_ + q) * N_ + (n0 + row)) * DOUT + e] = lat;
    }
}

extern "C" void kernel_launch(void* const* d_in, const int* in_sizes, int n_in,
                              void* d_out, int out_size, void* d_ws, size_t ws_size,
                              hipStream_t stream)
{
    const float* theta = (const float*)d_in[0];
    const float* tpar  = (const float*)d_in[1];
    const float* A     = (const float*)d_in[2];
    const float* X     = (const float*)d_in[3];
    const float* fcw   = (const float*)d_in[4];
    const float* fcb   = (const float*)d_in[5];
    const float* cw    = (const float*)d_in[6];
    const float* cb    = (const float*)d_in[7];
    const float* p0    = (const float*)d_in[8];
    const float* p1    = (const float*)d_in[9];

    __hip_bfloat16* xwt = (__hip_bfloat16*)d_ws;   // 4 MiB

    prep_xw<<<B_ * R_ * (N_ / 64), 256, 0, stream>>>(theta, tpar, X, fcw, xwt);
    fused_main<<<B_ * (N_ / 32), 256, 0, stream>>>(A, xwt, fcb, cw, cb, p0, p1,
                                                   (float*)d_out);
}

// Round 6
// 138.304 us; speedup vs baseline: 1.4897x; 1.4897x over previous
//
#include <hip/hip_runtime.h>
#include <hip/hip_bf16.h>

typedef __attribute__((ext_vector_type(8))) short  bf16x8;
typedef __attribute__((ext_vector_type(4))) float  f32x4;
typedef __attribute__((ext_vector_type(4))) int    i32x4;
typedef __attribute__((address_space(3))) void       as3void;
typedef const __attribute__((address_space(1))) void as1void;

#define B_   8
#define R_   4
#define N_   2048
#define S_   6
#define DIN  32
#define DOUT 32
#define NT   16    // K-supertiles of BK=128

// ---------------------------------------------------------------------------
// Pre-kernel: XW_T[b][r][e][m] = bf16( coef[r] * sum_d X[b,r,m,d] * fc_w[r,d,e] )
// ---------------------------------------------------------------------------
__global__ __launch_bounds__(256) void prep_xw(
    const float* __restrict__ theta, const float* __restrict__ tpar,
    const float* __restrict__ X,     const float* __restrict__ fcw,
    __hip_bfloat16* __restrict__ xwt)
{
    int br    = blockIdx.x >> 5;
    int mtile = blockIdx.x & 31;
    int r     = br & 3;
    int t     = threadIdx.x;
    int m     = mtile * 64 + (t & 63);
    int egrp  = t >> 6;

    float coef = 0.f;
#pragma unroll
    for (int s = 0; s < S_; ++s) coef += theta[r * S_ + s] * tpar[r * S_ + s];

    const float* xrow = X + ((size_t)br * N_ + m) * DIN;
    float xr[DIN];
#pragma unroll
    for (int i = 0; i < DIN / 4; ++i) {
        f32x4 v = *(const f32x4*)(xrow + i * 4);
        xr[i * 4 + 0] = v.x; xr[i * 4 + 1] = v.y;
        xr[i * 4 + 2] = v.z; xr[i * 4 + 3] = v.w;
    }
#pragma unroll
    for (int eb = 0; eb < 8; ++eb) {
        int e = egrp * 8 + eb;
        float acc = 0.f;
#pragma unroll
        for (int d = 0; d < DIN; ++d) acc += xr[d] * fcw[(r * DIN + d) * DOUT + e];
        xwt[((size_t)br * DOUT + e) * N_ + m] = __float2bfloat16(coef * acc);
    }
}

// ---------------------------------------------------------------------------
// Main fused kernel — EXACT R4 skeleton (best: 138.5us) + K-PHASE ROTATION.
// 4 waves/block (wave r = relation r), 16-row n-tile, BK=128 supertiles,
// global_load_lds DMA double-buffered, counted vmcnt(16), no K-loop barriers.
// NEW: each wave walks K-tiles starting at kt0=(bid+4r)&15, wrapping mod 16,
// so concurrent streams cover all 16 kt phases -> HBM channel bits [8:12]
// are uniformly populated at every instant (fixes 8KB-stride channel camping).
// ---------------------------------------------------------------------------
__global__ __launch_bounds__(256) void fused_main(
    const float* __restrict__ A,   const __hip_bfloat16* __restrict__ xwt,
    const float* __restrict__ fcb, const float* __restrict__ cw,
    const float* __restrict__ cb,  const float* __restrict__ p0p,
    const float* __restrict__ p1p, float* __restrict__ out)
{
    __shared__ char smem[65536];   // [buf(2)][wave(4)][16 rows][128 k f32]

    int bid  = blockIdx.x;
    int b    = bid >> 7;
    int tile = bid & 127;
    int n0   = tile * 16;
    int t    = threadIdx.x;
    int r    = t >> 6;
    int l    = t & 63;
    int row16 = l & 15;
    int kg    = l >> 4;
    int swzr  = (row16 & 7) << 4;
    int ldsbase = r * 8192;
    int hl   = l >> 5;
    int l31  = l & 31;
    int kt0  = (bid + r * 4) & 15;   // per-wave K start phase

    // per-lane DMA source pointers: instr i covers rows {2i, 2i+1} x 512B,
    // XOR swizzle pre-applied within each row's 512B run (linear LDS dest, G21).
    const char* Ab = (const char*)(A + (((size_t)(b * R_ + r)) * N_ + n0) * N_);
    const char* srcp[8];
#pragma unroll
    for (int i = 0; i < 8; ++i) {
        int row = 2 * i + hl;
        srcp[i] = Ab + (size_t)row * (N_ * 4) + ((l31 * 16) ^ ((row & 7) << 4));
    }

    // B pointers: fragment (e = eh*16+row16, k = pkt*128 + ks*32 + kg*8)
    const ushort* xw  = (const ushort*)xwt + (size_t)(b * R_ + r) * DOUT * N_;
    const ushort* bp0 = xw + (size_t)row16 * N_        + kg * 8;
    const ushort* bp1 = xw + (size_t)(16 + row16) * N_ + kg * 8;

#define STAGE_A(CUR, KT) do {                                                    \
    int pkt_ = (kt0 + (KT)) & 15;                                                \
    _Pragma("unroll")                                                            \
    for (int i_ = 0; i_ < 8; ++i_) {                                             \
        __builtin_amdgcn_global_load_lds(                                        \
            (as1void*)(srcp[i_] + (size_t)pkt_ * 512),                           \
            (as3void*)&smem[(CUR) * 32768 + ldsbase + i_ * 1024], 16, 0, 0);     \
    } } while (0)

#define LOADB(P, KT) do {                                                        \
    int pkb_ = (kt0 + (KT)) & 15;                                                \
    asm volatile("global_load_dwordx4 %0, %1, off" : "=v"(P##0) : "v"(bp0 + pkb_ * 128 +  0)); \
    asm volatile("global_load_dwordx4 %0, %1, off" : "=v"(P##1) : "v"(bp0 + pkb_ * 128 + 32)); \
    asm volatile("global_load_dwordx4 %0, %1, off" : "=v"(P##2) : "v"(bp0 + pkb_ * 128 + 64)); \
    asm volatile("global_load_dwordx4 %0, %1, off" : "=v"(P##3) : "v"(bp0 + pkb_ * 128 + 96)); \
    asm volatile("global_load_dwordx4 %0, %1, off" : "=v"(P##4) : "v"(bp1 + pkb_ * 128 +  0)); \
    asm volatile("global_load_dwordx4 %0, %1, off" : "=v"(P##5) : "v"(bp1 + pkb_ * 128 + 32)); \
    asm volatile("global_load_dwordx4 %0, %1, off" : "=v"(P##6) : "v"(bp1 + pkb_ * 128 + 64)); \
    asm volatile("global_load_dwordx4 %0, %1, off" : "=v"(P##7) : "v"(bp1 + pkb_ * 128 + 96)); \
    } while (0)

    f32x4 acc0 = {0.f, 0.f, 0.f, 0.f};
    f32x4 acc1 = {0.f, 0.f, 0.f, 0.f};
    i32x4 bc0, bc1, bc2, bc3, bc4, bc5, bc6, bc7;
    i32x4 bn0, bn1, bn2, bn3, bn4, bn5, bn6, bn7;

    STAGE_A(0, 0);
    LOADB(bc, 0);

#pragma unroll 2
    for (int kt = 0; kt < NT; ++kt) {
        int cur = kt & 1;
        __builtin_amdgcn_sched_barrier(0);
        if (kt < NT - 1) {
            STAGE_A(cur ^ 1, kt + 1);
            LOADB(bn, kt + 1);
            __builtin_amdgcn_sched_barrier(0);
            asm volatile("s_waitcnt vmcnt(16)" ::: "memory");  // cur's 16 done
        } else {
            __builtin_amdgcn_sched_barrier(0);
            asm volatile("s_waitcnt vmcnt(0)" ::: "memory");
        }
        __builtin_amdgcn_sched_barrier(0);

        {   // COMPUTE on buf[cur]: 4 MFMA k-steps of 32
            const char* abuf = &smem[cur * 32768 + ldsbase];
            int rbase = row16 * 512;
#define KSTEP(KS, BA, BB) do {                                                   \
    f32x4 lo = *(const f32x4*)(abuf + rbase + (((KS) * 128 + kg * 32 +  0) ^ swzr)); \
    f32x4 hi = *(const f32x4*)(abuf + rbase + (((KS) * 128 + kg * 32 + 16) ^ swzr)); \
    i32x4 av;                                                                    \
    asm("v_cvt_pk_bf16_f32 %0, %1, %2" : "=v"(av.x) : "v"(lo.x), "v"(lo.y));     \
    asm("v_cvt_pk_bf16_f32 %0, %1, %2" : "=v"(av.y) : "v"(lo.z), "v"(lo.w));     \
    asm("v_cvt_pk_bf16_f32 %0, %1, %2" : "=v"(av.z) : "v"(hi.x), "v"(hi.y));     \
    asm("v_cvt_pk_bf16_f32 %0, %1, %2" : "=v"(av.w) : "v"(hi.z), "v"(hi.w));     \
    bf16x8 af = __builtin_bit_cast(bf16x8, av);                                  \
    acc0 = __builtin_amdgcn_mfma_f32_16x16x32_bf16(af, __builtin_bit_cast(bf16x8, BA), acc0, 0, 0, 0); \
    acc1 = __builtin_amdgcn_mfma_f32_16x16x32_bf16(af, __builtin_bit_cast(bf16x8, BB), acc1, 0, 0, 0); \
    } while (0)
            KSTEP(0, bc0, bc4);
            KSTEP(1, bc1, bc5);
            KSTEP(2, bc2, bc6);
            KSTEP(3, bc3, bc7);
#undef KSTEP
        }
        bc0 = bn0; bc1 = bn1; bc2 = bn2; bc3 = bn3;
        bc4 = bn4; bc5 = bn5; bc6 = bn6; bc7 = bn7;
    }
#undef STAGE_A
#undef LOADB

    float p0 = p0p[0], p1 = p1p[0];

    __syncthreads();   // all waves done with A buffers before hlds overlays smem
    float (*hlds)[16][DOUT + 1] = (float (*)[16][DOUT + 1])(void*)smem;
#pragma unroll
    for (int j = 0; j < 4; ++j) {
        int rw = kg * 4 + j;
        float v0 = acc0[j] + fcb[r * DOUT + row16];
        float v1 = acc1[j] + fcb[r * DOUT + 16 + row16];
        hlds[r][rw][row16]      = v0 >= 0.f ? v0 : p0 * v0;
        hlds[r][rw][16 + row16] = v1 >= 0.f ? v1 : p0 * v1;
    }
    __syncthreads();

    int q = r;
    float c0 = cw[q * R_ + 0], c1 = cw[q * R_ + 1];
    float c2 = cw[q * R_ + 2], c3 = cw[q * R_ + 3];
    float cbq = cb[q];
    int e  = l & 31;
    int rg = l >> 5;
#pragma unroll
    for (int i = 0; i < 8; ++i) {
        int row = rg * 8 + i;
        float mx = cbq + c0 * hlds[0][row][e] + c1 * hlds[1][row][e]
                       + c2 * hlds[2][row][e] + c3 * hlds[3][row][e];
        float lat = mx >= 0.f ? mx : p1 * mx;
        out[(((size_t)b * R_ + q) * N_ + (n0 + row)) * DOUT + e] = lat;
    }
}

extern "C" void kernel_launch(void* const* d_in, const int* in_sizes, int n_in,
                              void* d_out, int out_size, void* d_ws, size_t ws_size,
                              hipStream_t stream)
{
    const float* theta = (const float*)d_in[0];
    const float* tpar  = (const float*)d_in[1];
    const float* A     = (const float*)d_in[2];
    const float* X     = (const float*)d_in[3];
    const float* fcw   = (const float*)d_in[4];
    const float* fcb   = (const float*)d_in[5];
    const float* cw    = (const float*)d_in[6];
    const float* cb    = (const float*)d_in[7];
    const float* p0    = (const float*)d_in[8];
    const float* p1    = (const float*)d_in[9];

    __hip_bfloat16* xwt = (__hip_bfloat16*)d_ws;   // 4 MiB

    prep_xw<<<B_ * R_ * (N_ / 64), 256, 0, stream>>>(theta, tpar, X, fcw, xwt);
    fused_main<<<B_ * (N_ / 16), 256, 0, stream>>>(A, xwt, fcb, cw, cb, p0, p1,
                                                   (float*)d_out);
}

// Round 7
// 137.980 us; speedup vs baseline: 1.4932x; 1.0023x over previous
//
#include <hip/hip_runtime.h>
#include <hip/hip_bf16.h>

typedef __attribute__((ext_vector_type(8))) short  bf16x8;
typedef __attribute__((ext_vector_type(4))) float  f32x4;
typedef __attribute__((ext_vector_type(4))) int    i32x4;
typedef __attribute__((address_space(3))) void       as3void;
typedef const __attribute__((address_space(1))) void as1void;

#define B_   8
#define R_   4
#define N_   2048
#define S_   6
#define DIN  32
#define DOUT 32
#define NT   16    // K-supertiles of BK=128

// ---------------------------------------------------------------------------
// Pre-kernel: XW_T[b][r][e][m] = bf16( coef[r] * sum_d X[b,r,m,d] * fc_w[r,d,e] )
// ---------------------------------------------------------------------------
__global__ __launch_bounds__(256) void prep_xw(
    const float* __restrict__ theta, const float* __restrict__ tpar,
    const float* __restrict__ X,     const float* __restrict__ fcw,
    __hip_bfloat16* __restrict__ xwt)
{
    int br    = blockIdx.x >> 5;
    int mtile = blockIdx.x & 31;
    int r     = br & 3;
    int t     = threadIdx.x;
    int m     = mtile * 64 + (t & 63);
    int egrp  = t >> 6;

    float coef = 0.f;
#pragma unroll
    for (int s = 0; s < S_; ++s) coef += theta[r * S_ + s] * tpar[r * S_ + s];

    const float* xrow = X + ((size_t)br * N_ + m) * DIN;
    float xr[DIN];
#pragma unroll
    for (int i = 0; i < DIN / 4; ++i) {
        f32x4 v = *(const f32x4*)(xrow + i * 4);
        xr[i * 4 + 0] = v.x; xr[i * 4 + 1] = v.y;
        xr[i * 4 + 2] = v.z; xr[i * 4 + 3] = v.w;
    }
#pragma unroll
    for (int eb = 0; eb < 8; ++eb) {
        int e = egrp * 8 + eb;
        float acc = 0.f;
#pragma unroll
        for (int d = 0; d < DIN; ++d) acc += xr[d] * fcw[(r * DIN + d) * DOUT + e];
        xwt[((size_t)br * DOUT + e) * N_ + m] = __float2bfloat16(coef * acc);
    }
}

// ---------------------------------------------------------------------------
// Main fused kernel — EXACT R4 skeleton (best: 138.5us) with ONE change:
// A DMA loads carry the NT (non-temporal) cache policy (aux=2). A has zero
// reuse; NT makes its lines evict-first in L2 so the 4MB xwt B-matrix stays
// L2-resident instead of being continuously evicted by the 537MB A stream
// (H1: B-side L2 misses were adding ~250MB of hidden HBM traffic).
// Everything else unchanged: 4 waves/block (wave r = relation r), 16-row
// n-tile, BK=128 supertiles, global_load_lds DMA double-buffered, counted
// vmcnt(16), no K-loop barriers, source-side XOR swizzle (G21).
// ---------------------------------------------------------------------------
__global__ __launch_bounds__(256) void fused_main(
    const float* __restrict__ A,   const __hip_bfloat16* __restrict__ xwt,
    const float* __restrict__ fcb, const float* __restrict__ cw,
    const float* __restrict__ cb,  const float* __restrict__ p0p,
    const float* __restrict__ p1p, float* __restrict__ out)
{
    __shared__ char smem[65536];   // [buf(2)][wave(4)][16 rows][128 k f32]

    int bid  = blockIdx.x;
    int b    = bid >> 7;
    int tile = bid & 127;
    int n0   = tile * 16;
    int t    = threadIdx.x;
    int r    = t >> 6;
    int l    = t & 63;
    int row16 = l & 15;
    int kg    = l >> 4;
    int swzr  = (row16 & 7) << 4;
    int ldsbase = r * 8192;
    int hl   = l >> 5;
    int l31  = l & 31;

    // per-lane DMA source pointers: instr i covers rows {2i, 2i+1} x 512B,
    // XOR swizzle pre-applied within each row's 512B run (linear LDS dest, G21).
    const char* Ab = (const char*)(A + (((size_t)(b * R_ + r)) * N_ + n0) * N_);
    const char* srcp[8];
#pragma unroll
    for (int i = 0; i < 8; ++i) {
        int row = 2 * i + hl;
        srcp[i] = Ab + (size_t)row * (N_ * 4) + ((l31 * 16) ^ ((row & 7) << 4));
    }

    // B pointers: fragment (e = eh*16+row16, k = kt*128 + ks*32 + kg*8)
    const ushort* xw  = (const ushort*)xwt + (size_t)(b * R_ + r) * DOUT * N_;
    const ushort* bp0 = xw + (size_t)row16 * N_        + kg * 8;
    const ushort* bp1 = xw + (size_t)(16 + row16) * N_ + kg * 8;

#define STAGE_A(CUR, KT) do {                                                    \
    _Pragma("unroll")                                                            \
    for (int i_ = 0; i_ < 8; ++i_) {                                             \
        __builtin_amdgcn_global_load_lds(                                        \
            (as1void*)(srcp[i_] + (size_t)(KT) * 512),                           \
            (as3void*)&smem[(CUR) * 32768 + ldsbase + i_ * 1024], 16, 0, 2);     \
    } } while (0)   /* aux=2: NT (non-temporal) — A is evict-first in L2 */

#define LOADB(P, KT) do {                                                        \
    asm volatile("global_load_dwordx4 %0, %1, off" : "=v"(P##0) : "v"(bp0 + (KT) * 128 +  0)); \
    asm volatile("global_load_dwordx4 %0, %1, off" : "=v"(P##1) : "v"(bp0 + (KT) * 128 + 32)); \
    asm volatile("global_load_dwordx4 %0, %1, off" : "=v"(P##2) : "v"(bp0 + (KT) * 128 + 64)); \
    asm volatile("global_load_dwordx4 %0, %1, off" : "=v"(P##3) : "v"(bp0 + (KT) * 128 + 96)); \
    asm volatile("global_load_dwordx4 %0, %1, off" : "=v"(P##4) : "v"(bp1 + (KT) * 128 +  0)); \
    asm volatile("global_load_dwordx4 %0, %1, off" : "=v"(P##5) : "v"(bp1 + (KT) * 128 + 32)); \
    asm volatile("global_load_dwordx4 %0, %1, off" : "=v"(P##6) : "v"(bp1 + (KT) * 128 + 64)); \
    asm volatile("global_load_dwordx4 %0, %1, off" : "=v"(P##7) : "v"(bp1 + (KT) * 128 + 96)); \
    } while (0)

    f32x4 acc0 = {0.f, 0.f, 0.f, 0.f};
    f32x4 acc1 = {0.f, 0.f, 0.f, 0.f};
    i32x4 bc0, bc1, bc2, bc3, bc4, bc5, bc6, bc7;
    i32x4 bn0, bn1, bn2, bn3, bn4, bn5, bn6, bn7;

    STAGE_A(0, 0);
    LOADB(bc, 0);

#pragma unroll 2
    for (int kt = 0; kt < NT; ++kt) {
        int cur = kt & 1;
        __builtin_amdgcn_sched_barrier(0);
        if (kt < NT - 1) {
            STAGE_A(cur ^ 1, kt + 1);
            LOADB(bn, kt + 1);
            __builtin_amdgcn_sched_barrier(0);
            asm volatile("s_waitcnt vmcnt(16)" ::: "memory");  // cur's 16 done
        } else {
            __builtin_amdgcn_sched_barrier(0);
            asm volatile("s_waitcnt vmcnt(0)" ::: "memory");
        }
        __builtin_amdgcn_sched_barrier(0);

        {   // COMPUTE on buf[cur]: 4 MFMA k-steps of 32
            const char* abuf = &smem[cur * 32768 + ldsbase];
            int rbase = row16 * 512;
#define KSTEP(KS, BA, BB) do {                                                   \
    f32x4 lo = *(const f32x4*)(abuf + rbase + (((KS) * 128 + kg * 32 +  0) ^ swzr)); \
    f32x4 hi = *(const f32x4*)(abuf + rbase + (((KS) * 128 + kg * 32 + 16) ^ swzr)); \
    i32x4 av;                                                                    \
    asm("v_cvt_pk_bf16_f32 %0, %1, %2" : "=v"(av.x) : "v"(lo.x), "v"(lo.y));     \
    asm("v_cvt_pk_bf16_f32 %0, %1, %2" : "=v"(av.y) : "v"(lo.z), "v"(lo.w));     \
    asm("v_cvt_pk_bf16_f32 %0, %1, %2" : "=v"(av.z) : "v"(hi.x), "v"(hi.y));     \
    asm("v_cvt_pk_bf16_f32 %0, %1, %2" : "=v"(av.w) : "v"(hi.z), "v"(hi.w));     \
    bf16x8 af = __builtin_bit_cast(bf16x8, av);                                  \
    acc0 = __builtin_amdgcn_mfma_f32_16x16x32_bf16(af, __builtin_bit_cast(bf16x8, BA), acc0, 0, 0, 0); \
    acc1 = __builtin_amdgcn_mfma_f32_16x16x32_bf16(af, __builtin_bit_cast(bf16x8, BB), acc1, 0, 0, 0); \
    } while (0)
            KSTEP(0, bc0, bc4);
            KSTEP(1, bc1, bc5);
            KSTEP(2, bc2, bc6);
            KSTEP(3, bc3, bc7);
#undef KSTEP
        }
        bc0 = bn0; bc1 = bn1; bc2 = bn2; bc3 = bn3;
        bc4 = bn4; bc5 = bn5; bc6 = bn6; bc7 = bn7;
    }
#undef STAGE_A
#undef LOADB

    float p0 = p0p[0], p1 = p1p[0];

    __syncthreads();   // all waves done with A buffers before hlds overlays smem
    float (*hlds)[16][DOUT + 1] = (float (*)[16][DOUT + 1])(void*)smem;
#pragma unroll
    for (int j = 0; j < 4; ++j) {
        int rw = kg * 4 + j;
        float v0 = acc0[j] + fcb[r * DOUT + row16];
        float v1 = acc1[j] + fcb[r * DOUT + 16 + row16];
        hlds[r][rw][row16]      = v0 >= 0.f ? v0 : p0 * v0;
        hlds[r][rw][16 + row16] = v1 >= 0.f ? v1 : p0 * v1;
    }
    __syncthreads();

    int q = r;
    float c0 = cw[q * R_ + 0], c1 = cw[q * R_ + 1];
    float c2 = cw[q * R_ + 2], c3 = cw[q * R_ + 3];
    float cbq = cb[q];
    int e  = l & 31;
    int rg = l >> 5;
#pragma unroll
    for (int i = 0; i < 8; ++i) {
        int row = rg * 8 + i;
        float mx = cbq + c0 * hlds[0][row][e] + c1 * hlds[1][row][e]
                       + c2 * hlds[2][row][e] + c3 * hlds[3][row][e];
        float lat = mx >= 0.f ? mx : p1 * mx;
        out[(((size_t)b * R_ + q) * N_ + (n0 + row)) * DOUT + e] = lat;
    }
}

extern "C" void kernel_launch(void* const* d_in, const int* in_sizes, int n_in,
                              void* d_out, int out_size, void* d_ws, size_t ws_size,
                              hipStream_t stream)
{
    const float* theta = (const float*)d_in[0];
    const float* tpar  = (const float*)d_in[1];
    const float* A     = (const float*)d_in[2];
    const float* X     = (const float*)d_in[3];
    const float* fcw   = (const float*)d_in[4];
    const float* fcb   = (const float*)d_in[5];
    const float* cw    = (const float*)d_in[6];
    const float* cb    = (const float*)d_in[7];
    const float* p0    = (const float*)d_in[8];
    const float* p1    = (const float*)d_in[9];

    __hip_bfloat16* xwt = (__hip_bfloat16*)d_ws;   // 4 MiB

    prep_xw<<<B_ * R_ * (N_ / 64), 256, 0, stream>>>(theta, tpar, X, fcw, xwt);
    fused_main<<<B_ * (N_ / 16), 256, 0, stream>>>(A, xwt, fcb, cw, cb, p0, p1,
                                                   (float*)d_out);
}